// Round 1
// baseline (1145.593 us; speedup 1.0000x reference)
//
#include <hip/hip_runtime.h>
#include <math.h>

// LiftSplatShoot constants
#define DNUM 41
#define FH 8
#define FW 22
#define CAMC 64
#define NB 8
#define NCAM 6
#define BN 48
#define NXX 200
#define NXY 200
#define KVOX 40000          // NXX*NXY (NXZ=1)
#define CAM_CH (DNUM + CAMC)  // 105
#define HW (FH * FW)          // 176
#define CAM_STRIDE (CAM_CH * HW)  // 18480
#define OUT_PER_B (CAMC * KVOX)   // 2,560,000

// Replicates reference safe_inverse_3x3 in float32, same op order, no fma.
__device__ __forceinline__ void inv3x3(const float* __restrict__ m, float* __restrict__ o) {
  #pragma clang fp contract(off)
  float a=m[0], b=m[1], c=m[2];
  float d=m[3], e=m[4], f=m[5];
  float g=m[6], h=m[7], i=m[8];
  float A  =  e*i - f*h;
  float Bc = -(d*i - f*g);
  float Cc =  d*h - e*g;
  float Dc = -(b*i - c*h);
  float E  =  a*i - c*g;
  float F  = -(a*h - b*g);
  float G  =  b*f - c*e;
  float H  = -(a*f - c*d);
  float I  =  a*e - b*d;
  float det = fmaxf((a*A + b*Bc) + c*Cc, 1e-8f);
  o[0]=A/det;  o[1]=Dc/det; o[2]=G/det;
  o[3]=Bc/det; o[4]=E/det;  o[5]=H/det;
  o[6]=Cc/det; o[7]=F/det;  o[8]=I/det;
}

// Per-(b,n): P = inv(post_rots), M = rots @ inv(intrins). 18 floats each -> ws.
__global__ void lss_prep(const float* __restrict__ rots,
                         const float* __restrict__ intrins,
                         const float* __restrict__ post_rots,
                         float* __restrict__ ws) {
  #pragma clang fp contract(off)
  int bn = threadIdx.x;
  if (bn >= BN) return;
  float P[9], IC[9];
  inv3x3(post_rots + bn*9, P);
  inv3x3(intrins + bn*9, IC);
  const float* R = rots + bn*9;
  float* o = ws + bn*18;
  #pragma unroll
  for (int j = 0; j < 9; j++) o[j] = P[j];
  #pragma unroll
  for (int r = 0; r < 3; r++)
    #pragma unroll
    for (int k = 0; k < 3; k++)
      o[9 + r*3 + k] = (R[r*3+0]*IC[0+k] + R[r*3+1]*IC[3+k]) + R[r*3+2]*IC[6+k];
}

// One block (64 threads = 1 wave) per (bn, h, w) pixel.
__global__ __launch_bounds__(64) void lss_main(const float* __restrict__ cam_out,
                                               const float* __restrict__ trans,
                                               const float* __restrict__ post_trans,
                                               const float* __restrict__ ws,
                                               float* __restrict__ out) {
  #pragma clang fp contract(off)
  const int blk = blockIdx.x;         // 0 .. BN*HW-1
  const int bn  = blk / HW;
  const int pix = blk % HW;
  const int h   = pix / FW;
  const int w   = pix % FW;
  const int b   = bn / NCAM;
  const int tid = threadIdx.x;

  __shared__ float sP[9], sM[9], sPT[3], sTR[3];
  __shared__ float sDepth[DNUM];
  __shared__ int   sVoff[DNUM];

  if (tid < 9)       sP[tid]      = ws[bn*18 + tid];
  else if (tid < 18) sM[tid-9]    = ws[bn*18 + tid];
  else if (tid < 21) sPT[tid-18]  = post_trans[bn*3 + (tid-18)];
  else if (tid < 24) sTR[tid-21]  = trans[bn*3 + (tid-21)];
  __syncthreads();

  const int base = bn*CAM_STRIDE + h*FW + w;

  // ---- softmax over 41 depth logits (lanes 0..40 active, wave64 shuffles) ----
  float logit = (tid < DNUM) ? cam_out[base + tid*HW] : -INFINITY;
  float mx = logit;
  #pragma unroll
  for (int off = 32; off >= 1; off >>= 1) mx = fmaxf(mx, __shfl_xor(mx, off, 64));
  float e = expf(logit - mx);           // lanes >=41: expf(-inf)=0
  float s = e;
  #pragma unroll
  for (int off = 32; off >= 1; off >>= 1) s += __shfl_xor(s, off, 64);
  float depth = e / s;

  // ---- geometry + voxel index for lane's depth bin ----
  if (tid < DNUM) {
    // frustum point (np.linspace computed in f64, cast to f32)
    float fx = (float)((double)w * (351.0 / 21.0));
    float fy = (float)((double)h * (127.0 / 7.0));
    float fz = 4.0f + (float)tid;
    float p0 = fx - sPT[0], p1 = fy - sPT[1], p2 = fz - sPT[2];
    float q0 = (sP[0]*p0 + sP[1]*p1) + sP[2]*p2;
    float q1 = (sP[3]*p0 + sP[4]*p1) + sP[5]*p2;
    float q2 = (sP[6]*p0 + sP[7]*p1) + sP[8]*p2;
    float r0 = q0*q2, r1 = q1*q2, r2 = q2;
    float g0 = ((sM[0]*r0 + sM[1]*r1) + sM[2]*r2) + sTR[0];
    float g1 = ((sM[3]*r0 + sM[4]*r1) + sM[5]*r2) + sTR[1];
    float g2 = ((sM[6]*r0 + sM[7]*r1) + sM[8]*r2) + sTR[2];
    // gi = trunc((geom - (BX - DX/2)) / DX); BX-DX/2 = (-50,-50,-10) exactly
    int ix = (int)((g0 + 50.0f) / 0.5f);
    int iy = (int)((g1 + 50.0f) / 0.5f);
    int iz = (int)((g2 + 10.0f) / 20.0f);
    bool kept = (ix >= 0) & (ix < NXX) & (iy >= 0) & (iy < NXY) & (iz == 0);
    sVoff[tid]  = kept ? (ix*NXY + iy) : -1;
    sDepth[tid] = depth;
  }
  __syncthreads();

  // ---- scatter: thread = channel c, loop depth bins ----
  const float feat = cam_out[base + (DNUM + tid)*HW];
  float* outb = out + b*OUT_PER_B + tid*KVOX;
  #pragma unroll 1
  for (int d = 0; d < DNUM; d++) {
    int v = sVoff[d];                 // wave-uniform -> no divergence
    if (v >= 0) atomicAdd(outb + v, sDepth[d] * feat);
  }
}

extern "C" void kernel_launch(void* const* d_in, const int* in_sizes, int n_in,
                              void* d_out, int out_size, void* d_ws, size_t ws_size,
                              hipStream_t stream) {
  const float* cam_out    = (const float*)d_in[0];
  const float* rots       = (const float*)d_in[1];
  const float* trans      = (const float*)d_in[2];
  const float* intrins    = (const float*)d_in[3];
  const float* post_rots  = (const float*)d_in[4];
  const float* post_trans = (const float*)d_in[5];
  float* out = (float*)d_out;
  float* ws  = (float*)d_ws;

  // zero the voxel grid (segment_sum identity)
  hipMemsetAsync(out, 0, (size_t)out_size * sizeof(float), stream);

  lss_prep<<<1, 64, 0, stream>>>(rots, intrins, post_rots, ws);
  lss_main<<<BN * HW, 64, 0, stream>>>(cam_out, trans, post_trans, ws, out);
}

// Round 2
// 130.629 us; speedup vs baseline: 8.7698x; 8.7698x over previous
//
#include <hip/hip_runtime.h>
#include <math.h>

// LiftSplatShoot constants
#define DNUM 41
#define FH 8
#define FW 22
#define CAMC 64
#define NB 8
#define NCAM 6
#define BN 48
#define NXX 200
#define NXY 200
#define KVOX 40000              // NXX*NXY (NXZ=1)
#define CAM_CH (DNUM + CAMC)    // 105
#define HW (FH * FW)            // 176
#define CAM_STRIDE (CAM_CH * HW)  // 18480
#define OUT_PER_B (CAMC * KVOX)   // 2,560,000
#define SCRATCH_FLOATS (NB * KVOX * CAMC)   // 20,480,000 floats = 81.92 MB

// Replicates reference safe_inverse_3x3 in float32, same op order, no fma.
__device__ __forceinline__ void inv3x3(const float* __restrict__ m, float* __restrict__ o) {
  #pragma clang fp contract(off)
  float a=m[0], b=m[1], c=m[2];
  float d=m[3], e=m[4], f=m[5];
  float g=m[6], h=m[7], i=m[8];
  float A  =  e*i - f*h;
  float Bc = -(d*i - f*g);
  float Cc =  d*h - e*g;
  float Dc = -(b*i - c*h);
  float E  =  a*i - c*g;
  float F  = -(a*h - b*g);
  float G  =  b*f - c*e;
  float H  = -(a*f - c*d);
  float I  =  a*e - b*d;
  float det = fmaxf((a*A + b*Bc) + c*Cc, 1e-8f);
  o[0]=A/det;  o[1]=Dc/det; o[2]=G/det;
  o[3]=Bc/det; o[4]=E/det;  o[5]=H/det;
  o[6]=Cc/det; o[7]=F/det;  o[8]=I/det;
}

// Per-(b,n): P = inv(post_rots), M = rots @ inv(intrins). 18 floats each -> prep.
__global__ void lss_prep(const float* __restrict__ rots,
                         const float* __restrict__ intrins,
                         const float* __restrict__ post_rots,
                         float* __restrict__ prep) {
  #pragma clang fp contract(off)
  int bn = threadIdx.x;
  if (bn >= BN) return;
  float P[9], IC[9];
  inv3x3(post_rots + bn*9, P);
  inv3x3(intrins + bn*9, IC);
  const float* R = rots + bn*9;
  float* o = prep + bn*18;
  #pragma unroll
  for (int j = 0; j < 9; j++) o[j] = P[j];
  #pragma unroll
  for (int r = 0; r < 3; r++)
    #pragma unroll
    for (int k = 0; k < 3; k++)
      o[9 + r*3 + k] = (R[r*3+0]*IC[0+k] + R[r*3+1]*IC[3+k]) + R[r*3+2]*IC[6+k];
}

// One block (64 threads = 1 wave) per (bn, h, w) pixel.
// dst layout generic: addr = dst + b*OUT_PER_B + v*vox_stride + c*chan_stride
//   scratch path: vox_stride=CAMC, chan_stride=1   (channels contiguous -> coalesced atomics)
//   direct  path: vox_stride=1,    chan_stride=KVOX
__global__ __launch_bounds__(64) void lss_scatter(const float* __restrict__ cam_out,
                                                  const float* __restrict__ trans,
                                                  const float* __restrict__ post_trans,
                                                  const float* __restrict__ prep,
                                                  float* __restrict__ dst,
                                                  int vox_stride, int chan_stride) {
  #pragma clang fp contract(off)
  const int blk = blockIdx.x;         // 0 .. BN*HW-1
  const int bn  = blk / HW;
  const int pix = blk % HW;
  const int h   = pix / FW;
  const int w   = pix % FW;
  const int b   = bn / NCAM;
  const int tid = threadIdx.x;

  __shared__ float sP[9], sM[9], sPT[3], sTR[3];
  __shared__ float sDepth[DNUM];
  __shared__ int   sVoff[DNUM];

  if (tid < 9)       sP[tid]      = prep[bn*18 + tid];
  else if (tid < 18) sM[tid-9]    = prep[bn*18 + tid];
  else if (tid < 21) sPT[tid-18]  = post_trans[bn*3 + (tid-18)];
  else if (tid < 24) sTR[tid-21]  = trans[bn*3 + (tid-21)];
  __syncthreads();

  const int base = bn*CAM_STRIDE + h*FW + w;

  // ---- softmax over 41 depth logits (lanes 0..40 active, wave64 shuffles) ----
  float logit = (tid < DNUM) ? cam_out[base + tid*HW] : -INFINITY;
  float mx = logit;
  #pragma unroll
  for (int off = 32; off >= 1; off >>= 1) mx = fmaxf(mx, __shfl_xor(mx, off, 64));
  float e = expf(logit - mx);           // lanes >=41: expf(-inf)=0
  float s = e;
  #pragma unroll
  for (int off = 32; off >= 1; off >>= 1) s += __shfl_xor(s, off, 64);
  float depth = e / s;

  // ---- geometry + voxel index for lane's depth bin ----
  if (tid < DNUM) {
    float fx = (float)((double)w * (351.0 / 21.0));
    float fy = (float)((double)h * (127.0 / 7.0));
    float fz = 4.0f + (float)tid;
    float p0 = fx - sPT[0], p1 = fy - sPT[1], p2 = fz - sPT[2];
    float q0 = (sP[0]*p0 + sP[1]*p1) + sP[2]*p2;
    float q1 = (sP[3]*p0 + sP[4]*p1) + sP[5]*p2;
    float q2 = (sP[6]*p0 + sP[7]*p1) + sP[8]*p2;
    float r0 = q0*q2, r1 = q1*q2, r2 = q2;
    float g0 = ((sM[0]*r0 + sM[1]*r1) + sM[2]*r2) + sTR[0];
    float g1 = ((sM[3]*r0 + sM[4]*r1) + sM[5]*r2) + sTR[1];
    float g2 = ((sM[6]*r0 + sM[7]*r1) + sM[8]*r2) + sTR[2];
    int ix = (int)((g0 + 50.0f) / 0.5f);
    int iy = (int)((g1 + 50.0f) / 0.5f);
    int iz = (int)((g2 + 10.0f) / 20.0f);
    bool kept = (ix >= 0) & (ix < NXX) & (iy >= 0) & (iy < NXY) & (iz == 0);
    sVoff[tid]  = kept ? (ix*NXY + iy) : -1;
    sDepth[tid] = depth;
  }
  __syncthreads();

  // ---- scatter: thread = channel c, loop depth bins ----
  const float feat = cam_out[base + (DNUM + tid)*HW];
  float* outb = dst + (size_t)b*OUT_PER_B + tid*chan_stride;
  #pragma unroll 1
  for (int d = 0; d < DNUM; d++) {
    int v = sVoff[d];                 // wave-uniform -> no divergence
    if (v >= 0) atomicAdd(outb + v*vox_stride, sDepth[d] * feat);
  }
}

// (B, XY, C) -> (B, C, XY) tiled transpose; writes EVERY output element.
__global__ __launch_bounds__(256) void lss_transpose(const float* __restrict__ src,
                                                     float* __restrict__ out) {
  __shared__ float tile[64][65];
  const int b  = blockIdx.y;
  const int v0 = blockIdx.x * 64;                 // 625 * 64 = 40000 exactly
  const int tx = threadIdx.x & 63;
  const int ty = threadIdx.x >> 6;                // 0..3
  const float* s = src + ((size_t)b*KVOX + v0) * CAMC;
  #pragma unroll
  for (int r = ty; r < 64; r += 4)
    tile[r][tx] = s[r*CAMC + tx];                 // coalesced: 64 consecutive floats
  __syncthreads();
  float* dstp = out + (size_t)b*OUT_PER_B + v0;
  #pragma unroll
  for (int r = ty; r < 64; r += 4)
    dstp[(size_t)r*KVOX + tx] = tile[tx][r];      // coalesced: 64 consecutive floats
}

extern "C" void kernel_launch(void* const* d_in, const int* in_sizes, int n_in,
                              void* d_out, int out_size, void* d_ws, size_t ws_size,
                              hipStream_t stream) {
  const float* cam_out    = (const float*)d_in[0];
  const float* rots       = (const float*)d_in[1];
  const float* trans      = (const float*)d_in[2];
  const float* intrins    = (const float*)d_in[3];
  const float* post_rots  = (const float*)d_in[4];
  const float* post_trans = (const float*)d_in[5];
  float* out = (float*)d_out;
  float* ws  = (float*)d_ws;

  const size_t scratch_bytes = (size_t)SCRATCH_FLOATS * sizeof(float);
  const bool use_scratch = ws_size >= scratch_bytes + (size_t)BN*18*sizeof(float);
  float* prep = use_scratch ? (ws + SCRATCH_FLOATS) : ws;

  lss_prep<<<1, 64, 0, stream>>>(rots, intrins, post_rots, prep);

  if (use_scratch) {
    hipMemsetAsync(ws, 0, scratch_bytes, stream);
    lss_scatter<<<BN * HW, 64, 0, stream>>>(cam_out, trans, post_trans, prep,
                                            ws, CAMC, 1);
    dim3 g(KVOX / 64, NB);
    lss_transpose<<<g, 256, 0, stream>>>(ws, out);
  } else {
    hipMemsetAsync(out, 0, (size_t)out_size * sizeof(float), stream);
    lss_scatter<<<BN * HW, 64, 0, stream>>>(cam_out, trans, post_trans, prep,
                                            out, 1, KVOX);
  }
}